// Round 8
// baseline (347.074 us; speedup 1.0000x reference)
//
#include <hip/hip_runtime.h>
#include <math.h>

// Problem constants
#define Bsz  4096
#define Tlen 512
#define NE   30
#define NIN  5
#define HD10 10
#define B10  (Bsz*HD10)   // per-head plane: 40960 floats

typedef _Float16 h2v  __attribute__((ext_vector_type(2)));
typedef _Float16 f16x4 __attribute__((ext_vector_type(4)));
typedef _Float16 f16x8 __attribute__((ext_vector_type(8)));
typedef float    f32x4 __attribute__((ext_vector_type(4)));

__device__ __forceinline__ float fexp2(float x){ return __builtin_amdgcn_exp2f(x); }
__device__ __forceinline__ float frcp (float x){ return __builtin_amdgcn_rcpf(x); }
#define L2E 1.4426950408889634f

__device__ __forceinline__ void loadarr32(float arr[32], const float* bufrow){
  const float4* p4 = (const float4*)bufrow;
  #pragma unroll
  for (int q4=0;q4<8;q4++){ float4 vv=p4[q4]; arr[4*q4]=vv.x; arr[4*q4+1]=vv.y; arr[4*q4+2]=vv.z; arr[4*q4+3]=vv.w; }
}

// ---------------------------------------------------------------------------
// Kernel 1 (R17: 2 independent chains per block -- amortize the fixed stall).
// R16 post-mortem: bank-conflict fix (11.5M->3.2M) + trans cut were HIDDEN
// (dur 147->144). Step = 678 cy: 278 VALU issue (224 trans) + 66 MFMA + ~340
// correlated post-barrier stall (ds_read 120 + MFMA dep + 4-deep trans chain)
// that lockstep waves can't hide. R17: 16 waves / 1024 thr / grid 128; two
// DECORRELATED 16-batch chains per block. Per SIMD: 4 waves from 2 dep-graphs
// -> group B's trans issue fills group A's stall shadow. Fixed ~220-340 cy
// paid once per step for BOTH chains. Decisive test: neutral result =>
// fixed cost scales with waves => structural floor.
// Per-group structure identical to R16 (merged-rcp ACT 7 trans, stride-36 h
// rows, 2-ahead x prefetch, gate-packed MFMA rows).
// Fragment layouts (m89/m120-verified):
//   A[m=lane&15][k=(lane>>4)*8+j], B[k=(lane>>4)*8+j][n=lane&15],
//   D[m=(lane>>4)*4+r][n=lane&15].
// ---------------------------------------------------------------------------
#define XSTR 520          // f16 stride per batch in xh (padded)
#define HSTR 36           // f16 stride per batch in hb (18 words: 4-way banks)
#define GSZ  (16*HSTR)    // h plane per parity per group (576 f16)
#define HB_G (2*GSZ)      // hb per group (parity double-buffer)
#define XH_G (16*XSTR)    // xh per group

extern "C" __global__ void __launch_bounds__(1024,1)
lstm_k(const float* __restrict__ input, const float* __restrict__ w_ih,
       const float* __restrict__ w_hh, const float* __restrict__ b_ih,
       const float* __restrict__ b_hh, const float* __restrict__ in_proj_w,
       const float* __restrict__ in_proj_b,
       float* __restrict__ qo, float* __restrict__ ko, float* __restrict__ vo,
       float* __restrict__ ho)
{
  __shared__ __align__(16) _Float16 hb[2*HB_G];   // [grp][parity][n*HSTR+dim]
  __shared__ __align__(16) _Float16 xh[2*XH_G];   // [grp][n][t][8]
  const int tid  = threadIdx.x;
  const int grp  = __builtin_amdgcn_readfirstlane(tid >> 9);        // 0..1
  const int wvg  = __builtin_amdgcn_readfirstlane((tid >> 6) & 7);  // 0..7
  const int tg   = tid & 511;
  const int lane = tid & 63;
  const int n    = lane & 15;
  const int quad = lane >> 4;
  const int b0   = blockIdx.x * 32 + grp * 16;

  _Float16* hbg = hb + grp*HB_G;
  _Float16* xhg = xh + grp*XH_G;

  // ---- gate-packed A-frags: A row m = (dim 8*(m>>2)+wvg, gate m&3) ----
  f16x8 ah, ax;
  f32x4 bi;
  {
    const int r  = n & 3;               // gate for A row m=n
    const int qm = n >> 2;
    const int dA = 8*qm + wvg;          // dim for A row m=n
    const float sG = (r==2) ? (-2.f*L2E) : (-L2E);   // g gate: x2 scale for tanh
    const bool rv = (dA < NE);
    const int grow = rv ? (r*NE + dA) : 0;
    #pragma unroll
    for (int j=0;j<8;++j){
      const int k = quad*8 + j;
      ah[j] = (rv && k < NE) ? (_Float16)(sG*w_hh[grow*NE + k]) : (_Float16)0;
      ax[j] = (rv && quad==0 && j < NIN) ? (_Float16)(sG*w_ih[grow*NIN + j]) : (_Float16)0;
    }
    const int d = 8*quad + wvg;         // this lane's dim (D row 4q+rr = gate rr)
    #pragma unroll
    for (int rr=0;rr<4;++rr){
      const float sR = (rr==2) ? (-2.f*L2E) : (-L2E);
      bi[rr] = (d < NE) ? sR*(b_ih[rr*NE+d] + b_hh[rr*NE+d]) : 0.f;
    }
  }
  // zero h double-buffer and xh (slots 5..7 stay 0 forever)
  for (int i=tg; i<HB_G; i+=512) hbg[i] = (_Float16)0;
  for (int i=tg; i<XH_G; i+=512) xhg[i] = (_Float16)0;
  __syncthreads();

  float cc=0.f, hh=0.f;
  const int rdo  = n*HSTR + 8*quad;        // two b64 reads: dims 8q..8q+7
  const int wro  = n*HSTR + 8*quad + wvg;  // b16 write: my dim
  const int xoff = n*XSTR;
  f16x8 xB, xB2;
  f32x4 Cx, Cy;

#define LSTM_STEP(CIN, COUT, RB, WB, TT3) do{ \
    const f16x4 bl_ = *(const f16x4*)(hbg + (RB) + rdo); \
    const f16x4 bu_ = *(const f16x4*)(hbg + (RB) + rdo + 4); \
    union { f16x8 v; f16x4 h4[2]; } BU_; BU_.h4[0]=bl_; BU_.h4[1]=bu_; \
    COUT = __builtin_amdgcn_mfma_f32_16x16x32_f16(ax, xB, bi, 0,0,0); \
    xB = xB2; \
    xB2 = *(const f16x8*)(xhg + xoff + ((TT3)&63)*8); \
    f32x4 C_ = __builtin_amdgcn_mfma_f32_16x16x32_f16(ah, BU_.v, CIN, 0,0,0); \
    /* ACT: C_[0]=i, C_[1]=f, C_[2]=g(2x), C_[3]=o; 5 exp2 + 2 rcp */ \
    const float ei=fexp2(C_[0]), ef=fexp2(C_[1]); \
    const float eg=fexp2(C_[2]), eo=fexp2(C_[3]); \
    const float Af=1.f+ef, Bi_=1.f+ei, G2=1.f+eg; \
    const float BG = Bi_*G2; \
    const float R_ = frcp(Af*BG); \
    const float t2_ = (1.f-eg)*Af; \
    cc = fmaf(cc, BG, t2_) * R_; \
    const float e2=fexp2((2.f*L2E)*cc); \
    const float E2=1.f+e2; \
    hh = (e2-1.f)*frcp((1.f+eo)*E2); \
    hbg[(WB) + wro] = (_Float16)hh; \
    __syncthreads(); \
  }while(0)

  for (int tc = 0; tc < Tlen; tc += 64) {
    // stage 64 steps x 16 batches x 5 inputs -> f16 packed [n][t][8]
    // (prev chunk's final in-step barrier drained all xh reads)
    for (int i4 = tg; i4 < 1280; i4 += 512){
      const int nn = i4/80, e4 = i4%80;
      const float4 v4 = *(const float4*)(input + (size_t)(b0+nn)*(Tlen*NIN) + tc*NIN + e4*4);
      #pragma unroll
      for (int u=0;u<4;++u){
        const int e = e4*4+u;                        // 0..319 = t*5+c
        xhg[nn*XSTR + (e/5)*8 + (e%5)] = (_Float16)((&v4.x)[u]);
      }
    }
    __syncthreads();
    // prime: Cx <- x-proj(t=0); xB <- x(1); xB2 <- x(2)
    {
      const f16x8 x0 = *(const f16x8*)(xhg + xoff);
      Cx = __builtin_amdgcn_mfma_f32_16x16x32_f16(ax, x0, bi, 0,0,0);
      xB  = *(const f16x8*)(xhg + xoff + 8);
      xB2 = *(const f16x8*)(xhg + xoff + 16);
    }
    #pragma unroll 1
    for (int tl = 0; tl < 64; tl += 2) {
      LSTM_STEP(Cx, Cy, 0,    GSZ, tl+3);   // even: read parity0, write parity1
      LSTM_STEP(Cy, Cx, GSZ,  0,   tl+4);   // odd : read parity1, write parity0
    }
  }
#undef LSTM_STEP

  // ---- tail: stash fp32 h,c (reuse xhg as f32 scratch); project q,k,v ----
  float* hf = (float*)xhg;     // [16][36]
  float* cf = hf + 16*36;
  {
    hf[n*36 + 8*quad + wvg] = hh;   // dims 30,31 = exact 0 (harmless)
    cf[n*36 + 8*quad + wvg] = cc;
  }
  __syncthreads();
  for (int i = tg; i < 16*NE; i += 512){
    const int nn = i/NE, d = i%NE;
    ho[(size_t)(b0+nn)*NE + d] = hf[nn*36 + d];
  }
  const float QS = 0.31622776601683794f;     // 1/sqrt(10)
  for (int i = tg; i < 90*16; i += 512){
    const int o  = i % 90;
    const int nn = i / 90;
    const float* wrow = in_proj_w + o*NE;
    const float* src  = (o < NE) ? &hf[nn*36] : &cf[nn*36];
    float acc = in_proj_b[o];
    #pragma unroll
    for (int k2=0;k2<NE;k2++) acc = fmaf(wrow[k2], src[k2], acc);
    const int b = b0 + nn;
    if (o < 30)      { qo[(o/10)*B10 + b*10 + (o%10)] = acc * QS; }
    else if (o < 60) { const int u=o-30; ko[(u/10)*B10 + b*10 + (u%10)] = acc; }
    else             { const int u=o-60; vo[(u/10)*B10 + b*10 + (u%10)] = acc; }
  }
}

// ---------------------------------------------------------------------------
// Kernel 2 (R15, frozen): flash attention partials. Near issue floor;
// R15's rework was neutral -> attn is not the controllable bottleneck.
// ---------------------------------------------------------------------------
extern "C" __global__ void __launch_bounds__(256)
attn_part(const float* __restrict__ q, const float* __restrict__ k,
          const float* __restrict__ v, float* __restrict__ part, int nkeys)
{
  __shared__ __align__(16) float kst[2][640];   // [buf][64 keys x 10]
  __shared__ __align__(16) float vst[2][640];
  const int t    = threadIdx.x;
  const int qr   = blockIdx.x*256 + t;
  const int head = blockIdx.y;
  const int ks   = blockIdx.z;
  const float* kh = k + (size_t)head*B10;
  const float* vh = v + (size_t)head*B10;
  float qreg[10];
  {
    const float2* qp = (const float2*)(q + (size_t)head*B10 + (size_t)qr*10);
    #pragma unroll
    for (int i=0;i<5;i++){ float2 t2=qp[i]; qreg[2*i]=t2.x; qreg[2*i+1]=t2.y; }
  }
  float m = -INFINITY, l = 0.f, acc[10];
  #pragma unroll
  for (int d=0;d<10;d++) acc[d]=0.f;

  const int k0 = ks * nkeys;
  const int nt = nkeys >> 6;           // 64-key tiles
  // prefetch tile 0 into buf 0
  {
    const float4* ksrc = (const float4*)(kh + (size_t)k0*10);
    const float4* vsrc = (const float4*)(vh + (size_t)k0*10);
    for (int i=t; i<320; i+=256){
      if (i < 160) ((float4*)kst[0])[i]     = ksrc[i];
      else         ((float4*)vst[0])[i-160] = vsrc[i-160];
    }
  }
  #pragma unroll 1
  for (int ti=0; ti<nt; ++ti){
    __syncthreads();                   // staged tile ti visible; buf^1 reads done
    const int cur = ti & 1;
    if (ti+1 < nt){                    // prefetch next tile into other buf
      const int kt = k0 + ((ti+1)<<6);
      const float4* ksrc = (const float4*)(kh + (size_t)kt*10);
      const float4* vsrc = (const float4*)(vh + (size_t)kt*10);
      for (int i=t; i<320; i+=256){
        if (i < 160) ((float4*)kst[cur^1])[i]     = ksrc[i];
        else         ((float4*)vst[cur^1])[i-160] = vsrc[i-160];
      }
    }
    const float* kb = kst[cur];
    const float* vb = vst[cur];
    #pragma unroll 1
    for (int c8=0; c8<64; c8+=8){
      float s[8];
      #pragma unroll
      for (int u2=0;u2<4;u2++){        // 2 keys per iter: 5x float4 = 20 floats
        const float4* kp = (const float4*)(kb + (c8+2*u2)*10);
        const float4 A=kp[0], B4=kp[1], C4=kp[2], D4=kp[3], E4=kp[4];
        float s0 = qreg[0]*A.x;
        s0=fmaf(qreg[1],A.y,s0);  s0=fmaf(qreg[2],A.z,s0);  s0=fmaf(qreg[3],A.w,s0);
        s0=fmaf(qreg[4],B4.x,s0); s0=fmaf(qreg[5],B4.y,s0); s0=fmaf(qreg[6],B4.z,s0);
        s0=fmaf(qreg[7],B4.w,s0); s0=fmaf(qreg[8],C4.x,s0); s0=fmaf(qreg[9],C4.y,s0);
        float s1 = qreg[0]*C4.z;
        s1=fmaf(qreg[1],C4.w,s1); s1=fmaf(qreg[2],D4.x,s1); s1=fmaf(qreg[3],D4.y,s1);
        s1=fmaf(qreg[4],D4.z,s1); s1=fmaf(qreg[5],D4.w,s1); s1=fmaf(qreg[6],E4.x,s1);
        s1=fmaf(qreg[7],E4.y,s1); s1=fmaf(qreg[8],E4.z,s1); s1=fmaf(qreg[9],E4.w,s1);
        s[2*u2]=s0; s[2*u2+1]=s1;
      }
      float mc = fmaxf(fmaxf(fmaxf(s[0],s[1]),fmaxf(s[2],s[3])),
                       fmaxf(fmaxf(s[4],s[5]),fmaxf(s[6],s[7])));
      const float mnew = fmaxf(m, mc);
      const float corr = fexp2(L2E*(m - mnew));   // m=-inf first chunk -> 0
      l *= corr;
      #pragma unroll
      for (int d=0;d<10;d++) acc[d]*=corr;
      const float mB = L2E*mnew;
      #pragma unroll
      for (int u2=0;u2<4;u2++){
        const float p0 = fexp2(fmaf(s[2*u2],  L2E, -mB));
        const float p1 = fexp2(fmaf(s[2*u2+1],L2E, -mB));
        l += p0; l += p1;
        const float4* vp = (const float4*)(vb + (c8+2*u2)*10);
        const float4 A=vp[0], B4=vp[1], C4=vp[2], D4=vp[3], E4=vp[4];
        acc[0]=fmaf(p0,A.x,acc[0]);  acc[1]=fmaf(p0,A.y,acc[1]);
        acc[2]=fmaf(p0,A.z,acc[2]);  acc[3]=fmaf(p0,A.w,acc[3]);
        acc[4]=fmaf(p0,B4.x,acc[4]); acc[5]=fmaf(p0,B4.y,acc[5]);
        acc[6]=fmaf(p0,B4.z,acc[6]); acc[7]=fmaf(p0,B4.w,acc[7]);
        acc[8]=fmaf(p0,C4.x,acc[8]); acc[9]=fmaf(p0,C4.y,acc[9]);
        acc[0]=fmaf(p1,C4.z,acc[0]); acc[1]=fmaf(p1,C4.w,acc[1]);
        acc[2]=fmaf(p1,D4.x,acc[2]); acc[3]=fmaf(p1,D4.y,acc[3]);
        acc[4]=fmaf(p1,D4.z,acc[4]); acc[5]=fmaf(p1,D4.w,acc[5]);
        acc[6]=fmaf(p1,E4.x,acc[6]); acc[7]=fmaf(p1,E4.y,acc[7]);
        acc[8]=fmaf(p1,E4.z,acc[8]); acc[9]=fmaf(p1,E4.w,acc[9]);
      }
      m = mnew;
    }
  }
  float4 w0,w1,w2;
  w0.x=m;      w0.y=l;      w0.z=acc[0]; w0.w=acc[1];
  w1.x=acc[2]; w1.y=acc[3]; w1.z=acc[4]; w1.w=acc[5];
  w2.x=acc[6]; w2.y=acc[7]; w2.z=acc[8]; w2.w=acc[9];
  float4* pp4 = (float4*)(part + ((size_t)(head*Bsz + qr)*gridDim.z + ks)*12);
  pp4[0]=w0; pp4[1]=w1; pp4[2]=w2;
}

// ---------------------------------------------------------------------------
// Kernel 3 (R10, frozen): fused merge + out_proj + LN + MLP + LN + head.
// ---------------------------------------------------------------------------
extern "C" __global__ void __launch_bounds__(256)
tail_k(const float* __restrict__ part, int ns, const float* __restrict__ hn,
       const float* __restrict__ out_proj_w, const float* __restrict__ out_proj_b,
       const float* __restrict__ fc1_w, const float* __restrict__ fc1_b,
       const float* __restrict__ fc2_w, const float* __restrict__ fc2_b,
       const float* __restrict__ ln_g, const float* __restrict__ ln_b,
       const float* __restrict__ out_w, const float* __restrict__ out_b,
       float* __restrict__ out)
{
  __shared__ __align__(16) float buf[4][32];
  __shared__ float wl[2880];   // [0]=out_proj_w 900, [900]=fc1_w, [1800]=fc2_w, [2700]=out_w 90
  const int tidb = threadIdx.x;
  for (int i=tidb;i<900;i+=256) wl[i]       = out_proj_w[i];
  for (int i=tidb;i<900;i+=256) wl[900+i]   = fc1_w[i];
  for (int i=tidb;i<900;i+=256) wl[1800+i]  = fc2_w[i];
  if (tidb < 90) wl[2700+tidb] = out_w[tidb];
  const int wave = tidb >> 6;
  const int lane = tidb & 63;
  const int b = blockIdx.x*4 + wave;
  const bool act = (lane < NE);
  if (lane < 32) buf[wave][lane] = 0.f;
  __syncthreads();
  if (act) {
    const int head = lane/10, dd = lane%10;
    const float* p = part + ((size_t)(head*Bsz + b)*ns)*12;
    float M = -INFINITY, L = 0.f, O = 0.f;
    for (int i=0;i<ns;i++){
      const float mi = p[i*12], li = p[i*12+1], ai = p[i*12+2+dd];
      const float Mn = fmaxf(M, mi);
      const float cw = fexp2(L2E*(M - Mn));
      const float wi = fexp2(L2E*(mi - Mn));
      L = fmaf(li, wi, L*cw);
      O = fmaf(ai, wi, O*cw);
      M = Mn;
    }
    buf[wave][lane] = O / L;
  }
  __builtin_amdgcn_wave_barrier();
  float arr[32];
  loadarr32(arr, &buf[wave][0]);
  const float hv = act ? hn[b*NE+lane] : 0.f;
  float x = 0.f;
  if (act) {
    float a = out_proj_b[lane];
    #pragma unroll
    for (int k2=0;k2<NE;k2++) a = fmaf(wl[lane*NE+k2], arr[k2], a);
    x = a + hv;                       // attn_out + h_n
  }
  // LN1
  __builtin_amdgcn_wave_barrier();
  if (act) buf[wave][lane] = x;
  __builtin_amdgcn_wave_barrier();
  loadarr32(arr, &buf[wave][0]);
  float s1=0.f, s2=0.f;
  #pragma unroll
  for (int k2=0;k2<32;k2++){ s1+=arr[k2]; s2=fmaf(arr[k2],arr[k2],s2); }
  float mu = s1*(1.f/30.f);
  float var = s2*(1.f/30.f) - mu*mu;
  float rs = rsqrtf(var + 1e-5f);
  float x1 = 0.f;
  if (act) x1 = fmaf((x-mu)*rs, ln_g[lane], ln_b[lane]);
  // fc1 + exact GELU
  __builtin_amdgcn_wave_barrier();
  if (act) buf[wave][lane] = x1;
  __builtin_amdgcn_wave_barrier();
  loadarr32(arr, &buf[wave][0]);
  float gv = 0.f;
  if (act) {
    float a = fc1_b[lane];
    #pragma unroll
    for (int k2=0;k2<NE;k2++) a = fmaf(wl[900+lane*NE+k2], arr[k2], a);
    gv = 0.5f*a*(1.f + erff(a*0.70710678118654752f));
  }
  // fc2
  __builtin_amdgcn_wave_barrier();
  if (act) buf[wave][lane] = gv;
  __builtin_amdgcn_wave_barrier();
  loadarr32(arr, &buf[wave][0]);
  float y = 0.f;
  if (act) {
    float a = fc2_b[lane];
    #pragma unroll
    for (int k2=0;k2<NE;k2++) a = fmaf(wl[1800+lane*NE+k2], arr[k2], a);
    y = x1 + a;                        // residual x1 + fc
  }
  // LN2
  __builtin_amdgcn_wave_barrier();
  if (act) buf[wave][lane] = y;
  __builtin_amdgcn_wave_barrier();
  loadarr32(arr, &buf[wave][0]);
  s1=0.f; s2=0.f;
  #pragma unroll
  for (int k2=0;k2<32;k2++){ s1+=arr[k2]; s2=fmaf(arr[k2],arr[k2],s2); }
  mu = s1*(1.f/30.f);
  var = s2*(1.f/30.f) - mu*mu;
  rs = rsqrtf(var + 1e-5f);
  float x2 = 0.f;
  if (act) x2 = fmaf((y-mu)*rs, ln_g[lane], ln_b[lane]);
  // head: [3,30]
  __builtin_amdgcn_wave_barrier();
  if (act) buf[wave][lane] = x2;
  __builtin_amdgcn_wave_barrier();
  loadarr32(arr, &buf[wave][0]);
  if (lane < 3) {
    float a = out_b[lane];
    #pragma unroll
    for (int k2=0;k2<NE;k2++) a = fmaf(wl[2700+lane*NE+k2], arr[k2], a);
    out[b*3 + lane] = a;
  }
}

extern "C" void kernel_launch(void* const* d_in, const int* in_sizes, int n_in,
                              void* d_out, int out_size, void* d_ws, size_t ws_size,
                              hipStream_t stream)
{
  const float* input      = (const float*)d_in[0];
  const float* w_ih       = (const float*)d_in[1];
  const float* w_hh       = (const float*)d_in[2];
  const float* b_ih       = (const float*)d_in[3];
  const float* b_hh       = (const float*)d_in[4];
  const float* in_proj_w  = (const float*)d_in[5];
  const float* in_proj_b  = (const float*)d_in[6];
  const float* out_proj_w = (const float*)d_in[7];
  const float* out_proj_b = (const float*)d_in[8];
  const float* fc1_w      = (const float*)d_in[9];
  const float* fc1_b      = (const float*)d_in[10];
  const float* fc2_w      = (const float*)d_in[11];
  const float* fc2_b      = (const float*)d_in[12];
  const float* ln_g       = (const float*)d_in[13];
  const float* ln_b       = (const float*)d_in[14];
  const float* out_w      = (const float*)d_in[15];
  const float* out_b      = (const float*)d_in[16];

  float* ws = (float*)d_ws;
  float* qo   = ws;                 // [3][4096][10]
  float* ko   = ws + 122880;        // [3][4096][10]
  float* vo   = ws + 245760;        // [3][4096][10]
  float* hn   = ws + 368640;        // [4096][30]
  float* part = ws + 491520;        // [3][4096][NS][12]

  const size_t need32 = ((size_t)491520 + (size_t)3*4096*32*12) * 4;
  const size_t need16 = ((size_t)491520 + (size_t)3*4096*16*12) * 4;
  const int NS = (ws_size >= need32) ? 32 : (ws_size >= need16) ? 16 : 8;

  lstm_k<<<Bsz/32, 1024, 0, stream>>>(input, w_ih, w_hh, b_ih, b_hh,
                                      in_proj_w, in_proj_b, qo, ko, vo, hn);
  attn_part<<<dim3(Bsz/256, 3, NS), 256, 0, stream>>>(qo, ko, vo, part, Bsz/NS);
  tail_k<<<Bsz/4, 256, 0, stream>>>(part, NS, hn, out_proj_w, out_proj_b,
                                    fc1_w, fc1_b, fc2_w, fc2_b,
                                    ln_g, ln_b, out_w, out_b, (float*)d_out);
}

// Round 9
// 284.673 us; speedup vs baseline: 1.2192x; 1.2192x over previous
//
#include <hip/hip_runtime.h>
#include <math.h>

// Problem constants
#define Bsz  4096
#define Tlen 512
#define NE   30
#define NIN  5
#define HD10 10
#define B10  (Bsz*HD10)   // per-head plane: 40960 floats

typedef _Float16 h2v  __attribute__((ext_vector_type(2)));
typedef _Float16 f16x4 __attribute__((ext_vector_type(4)));
typedef _Float16 f16x8 __attribute__((ext_vector_type(8)));
typedef float    f32x4 __attribute__((ext_vector_type(4)));

__device__ __forceinline__ float fexp2(float x){ return __builtin_amdgcn_exp2f(x); }
__device__ __forceinline__ float frcp (float x){ return __builtin_amdgcn_rcpf(x); }
#define L2E 1.4426950408889634f

__device__ __forceinline__ void loadarr32(float arr[32], const float* bufrow){
  const float4* p4 = (const float4*)bufrow;
  #pragma unroll
  for (int q4=0;q4<8;q4++){ float4 vv=p4[q4]; arr[4*q4]=vv.x; arr[4*q4+1]=vv.y; arr[4*q4+2]=vv.z; arr[4*q4+3]=vv.w; }
}

// ---------------------------------------------------------------------------
// Kernel 1 (R18 = R16 revert; best known 145us).
// R17 lesson: 2 chains/block overlap gave 1.42x per-CU efficiency but the
// block-wide barrier coupled the groups AND grid halved to 128 CUs -> net
// 0.71x. With 256 chains on 256 CUs there is no decorrelated second chain
// per CU without lane waste (8-batch chains double trans issue).
// Step model: 224 cy trans-issue floor (7 trans/dim minimal: 5 exp2 + 2 rcp)
// + ~330 cy intrinsic recurrence latency (barrier -> ds_read 120 -> MFMA ->
// ACT chain -> write) = ~678 cy measured. Structural floor for this op.
// Fragment layouts (m89/m120-verified):
//   A[m=lane&15][k=(lane>>4)*8+j], B[k=(lane>>4)*8+j][n=lane&15],
//   D[m=(lane>>4)*4+r][n=lane&15].
// ---------------------------------------------------------------------------
#define XSTR 520   // f16 stride per batch in xh (padded)
#define HSTR 36    // f16 stride per batch in hb (18 words: 4-way banks)

extern "C" __global__ void __launch_bounds__(512,1)
lstm_k(const float* __restrict__ input, const float* __restrict__ w_ih,
       const float* __restrict__ w_hh, const float* __restrict__ b_ih,
       const float* __restrict__ b_hh, const float* __restrict__ in_proj_w,
       const float* __restrict__ in_proj_b,
       float* __restrict__ qo, float* __restrict__ ko, float* __restrict__ vo,
       float* __restrict__ ho)
{
  __shared__ __align__(16) _Float16 hb[2*16*HSTR];   // [parity][n*HSTR + dim]
  __shared__ __align__(16) _Float16 xh[16*XSTR];     // [n][t][8] f16 packed
  const int tid  = threadIdx.x;
  const int wv   = __builtin_amdgcn_readfirstlane(tid >> 6);   // 0..7 (SGPR)
  const int lane = tid & 63;
  const int n    = lane & 15;
  const int quad = lane >> 4;
  const int b0   = blockIdx.x * 16;

  // ---- gate-packed A-frags: A row m = (dim 8*(m>>2)+wv, gate m&3) ----
  f16x8 ah, ax;
  f32x4 bi;
  {
    const int r  = n & 3;               // gate for A row m=n
    const int qm = n >> 2;
    const int dA = 8*qm + wv;           // dim for A row m=n
    const float sG = (r==2) ? (-2.f*L2E) : (-L2E);   // g gate: x2 scale for tanh
    const bool rv = (dA < NE);
    const int grow = rv ? (r*NE + dA) : 0;
    #pragma unroll
    for (int j=0;j<8;++j){
      const int k = quad*8 + j;
      ah[j] = (rv && k < NE) ? (_Float16)(sG*w_hh[grow*NE + k]) : (_Float16)0;
      ax[j] = (rv && quad==0 && j < NIN) ? (_Float16)(sG*w_ih[grow*NIN + j]) : (_Float16)0;
    }
    const int d = 8*quad + wv;          // this lane's dim (D row 4q+rr = gate rr)
    #pragma unroll
    for (int rr=0;rr<4;++rr){
      const float sR = (rr==2) ? (-2.f*L2E) : (-L2E);
      bi[rr] = (d < NE) ? sR*(b_ih[rr*NE+d] + b_hh[rr*NE+d]) : 0.f;
    }
  }
  // zero h double-buffer and xh (slots 5..7 stay 0 forever)
  for (int i=tid; i<2*16*HSTR; i+=512) hb[i] = (_Float16)0;
  for (int i=tid; i<16*XSTR; i+=512) xh[i] = (_Float16)0;
  __syncthreads();

  float cc=0.f, hh=0.f;
  const int rdo  = n*HSTR + 8*quad;        // two b64 reads: dims 8q..8q+7
  const int wro  = n*HSTR + 8*quad + wv;   // b16 write: my dim
  const int xoff = n*XSTR;
  f16x8 xB, xB2;
  f32x4 Cx, Cy;

#define LSTM_STEP(CIN, COUT, RB, WB, TT3) do{ \
    const f16x4 bl_ = *(const f16x4*)(hb + (RB) + rdo); \
    const f16x4 bu_ = *(const f16x4*)(hb + (RB) + rdo + 4); \
    union { f16x8 v; f16x4 h4[2]; } BU_; BU_.h4[0]=bl_; BU_.h4[1]=bu_; \
    COUT = __builtin_amdgcn_mfma_f32_16x16x32_f16(ax, xB, bi, 0,0,0); \
    xB = xB2; \
    xB2 = *(const f16x8*)(xh + xoff + ((TT3)&63)*8); \
    f32x4 C_ = __builtin_amdgcn_mfma_f32_16x16x32_f16(ah, BU_.v, CIN, 0,0,0); \
    /* ACT: C_[0]=i, C_[1]=f, C_[2]=g(2x), C_[3]=o; 5 exp2 + 2 rcp */ \
    const float ei=fexp2(C_[0]), ef=fexp2(C_[1]); \
    const float eg=fexp2(C_[2]), eo=fexp2(C_[3]); \
    const float Af=1.f+ef, Bi_=1.f+ei, G2=1.f+eg; \
    const float BG = Bi_*G2; \
    const float R_ = frcp(Af*BG); \
    const float t2_ = (1.f-eg)*Af; \
    cc = fmaf(cc, BG, t2_) * R_; \
    const float e2=fexp2((2.f*L2E)*cc); \
    const float E2=1.f+e2; \
    hh = (e2-1.f)*frcp((1.f+eo)*E2); \
    hb[(WB) + wro] = (_Float16)hh; \
    __syncthreads(); \
  }while(0)

  for (int tc = 0; tc < Tlen; tc += 64) {
    // stage 64 steps x 16 batches x 5 inputs -> f16 packed [n][t][8]
    // (prev chunk's final in-step barrier drained all xh reads)
    for (int i4 = tid; i4 < 1280; i4 += 512){
      const int nn = i4/80, e4 = i4%80;
      const float4 v4 = *(const float4*)(input + (size_t)(b0+nn)*(Tlen*NIN) + tc*NIN + e4*4);
      #pragma unroll
      for (int u=0;u<4;++u){
        const int e = e4*4+u;                        // 0..319 = t*5+c
        xh[nn*XSTR + (e/5)*8 + (e%5)] = (_Float16)((&v4.x)[u]);
      }
    }
    __syncthreads();
    // prime: Cx <- x-proj(t=0); xB <- x(1); xB2 <- x(2)
    {
      const f16x8 x0 = *(const f16x8*)(xh + xoff);
      Cx = __builtin_amdgcn_mfma_f32_16x16x32_f16(ax, x0, bi, 0,0,0);
      xB  = *(const f16x8*)(xh + xoff + 8);
      xB2 = *(const f16x8*)(xh + xoff + 16);
    }
    #pragma unroll 1
    for (int tl = 0; tl < 64; tl += 2) {
      LSTM_STEP(Cx, Cy, 0,        16*HSTR, tl+3);   // even: read buf0, write buf1
      LSTM_STEP(Cy, Cx, 16*HSTR,  0,       tl+4);   // odd : read buf1, write buf0
    }
  }
#undef LSTM_STEP

  // ---- tail: stash fp32 h,c (reuse xh as f32 scratch); project q,k,v ----
  float* hf = (float*)xh;      // [16][36]
  float* cf = hf + 16*36;
  {
    hf[n*36 + 8*quad + wv] = hh;   // dims 30,31 = exact 0 (harmless)
    cf[n*36 + 8*quad + wv] = cc;
  }
  __syncthreads();
  for (int i = tid; i < 16*NE; i += 512){
    const int nn = i/NE, d = i%NE;
    ho[(size_t)(b0+nn)*NE + d] = hf[nn*36 + d];
  }
  const float QS = 0.31622776601683794f;     // 1/sqrt(10)
  for (int i = tid; i < 90*16; i += 512){
    const int o  = i % 90;
    const int nn = i / 90;
    const float* wrow = in_proj_w + o*NE;
    const float* src  = (o < NE) ? &hf[nn*36] : &cf[nn*36];
    float acc = in_proj_b[o];
    #pragma unroll
    for (int k2=0;k2<NE;k2++) acc = fmaf(wrow[k2], src[k2], acc);
    const int b = b0 + nn;
    if (o < 30)      { qo[(o/10)*B10 + b*10 + (o%10)] = acc * QS; }
    else if (o < 60) { const int u=o-30; ko[(u/10)*B10 + b*10 + (u%10)] = acc; }
    else             { const int u=o-60; vo[(u/10)*B10 + b*10 + (u%10)] = acc; }
  }
}

// ---------------------------------------------------------------------------
// Kernel 2 (R15, frozen): flash attention partials. Near issue floor;
// R15's rework was neutral -> attn is not the controllable bottleneck.
// ---------------------------------------------------------------------------
extern "C" __global__ void __launch_bounds__(256)
attn_part(const float* __restrict__ q, const float* __restrict__ k,
          const float* __restrict__ v, float* __restrict__ part, int nkeys)
{
  __shared__ __align__(16) float kst[2][640];   // [buf][64 keys x 10]
  __shared__ __align__(16) float vst[2][640];
  const int t    = threadIdx.x;
  const int qr   = blockIdx.x*256 + t;
  const int head = blockIdx.y;
  const int ks   = blockIdx.z;
  const float* kh = k + (size_t)head*B10;
  const float* vh = v + (size_t)head*B10;
  float qreg[10];
  {
    const float2* qp = (const float2*)(q + (size_t)head*B10 + (size_t)qr*10);
    #pragma unroll
    for (int i=0;i<5;i++){ float2 t2=qp[i]; qreg[2*i]=t2.x; qreg[2*i+1]=t2.y; }
  }
  float m = -INFINITY, l = 0.f, acc[10];
  #pragma unroll
  for (int d=0;d<10;d++) acc[d]=0.f;

  const int k0 = ks * nkeys;
  const int nt = nkeys >> 6;           // 64-key tiles
  // prefetch tile 0 into buf 0
  {
    const float4* ksrc = (const float4*)(kh + (size_t)k0*10);
    const float4* vsrc = (const float4*)(vh + (size_t)k0*10);
    for (int i=t; i<320; i+=256){
      if (i < 160) ((float4*)kst[0])[i]     = ksrc[i];
      else         ((float4*)vst[0])[i-160] = vsrc[i-160];
    }
  }
  #pragma unroll 1
  for (int ti=0; ti<nt; ++ti){
    __syncthreads();                   // staged tile ti visible; buf^1 reads done
    const int cur = ti & 1;
    if (ti+1 < nt){                    // prefetch next tile into other buf
      const int kt = k0 + ((ti+1)<<6);
      const float4* ksrc = (const float4*)(kh + (size_t)kt*10);
      const float4* vsrc = (const float4*)(vh + (size_t)kt*10);
      for (int i=t; i<320; i+=256){
        if (i < 160) ((float4*)kst[cur^1])[i]     = ksrc[i];
        else         ((float4*)vst[cur^1])[i-160] = vsrc[i-160];
      }
    }
    const float* kb = kst[cur];
    const float* vb = vst[cur];
    #pragma unroll 1
    for (int c8=0; c8<64; c8+=8){
      float s[8];
      #pragma unroll
      for (int u2=0;u2<4;u2++){        // 2 keys per iter: 5x float4 = 20 floats
        const float4* kp = (const float4*)(kb + (c8+2*u2)*10);
        const float4 A=kp[0], B4=kp[1], C4=kp[2], D4=kp[3], E4=kp[4];
        float s0 = qreg[0]*A.x;
        s0=fmaf(qreg[1],A.y,s0);  s0=fmaf(qreg[2],A.z,s0);  s0=fmaf(qreg[3],A.w,s0);
        s0=fmaf(qreg[4],B4.x,s0); s0=fmaf(qreg[5],B4.y,s0); s0=fmaf(qreg[6],B4.z,s0);
        s0=fmaf(qreg[7],B4.w,s0); s0=fmaf(qreg[8],C4.x,s0); s0=fmaf(qreg[9],C4.y,s0);
        float s1 = qreg[0]*C4.z;
        s1=fmaf(qreg[1],C4.w,s1); s1=fmaf(qreg[2],D4.x,s1); s1=fmaf(qreg[3],D4.y,s1);
        s1=fmaf(qreg[4],D4.z,s1); s1=fmaf(qreg[5],D4.w,s1); s1=fmaf(qreg[6],E4.x,s1);
        s1=fmaf(qreg[7],E4.y,s1); s1=fmaf(qreg[8],E4.z,s1); s1=fmaf(qreg[9],E4.w,s1);
        s[2*u2]=s0; s[2*u2+1]=s1;
      }
      float mc = fmaxf(fmaxf(fmaxf(s[0],s[1]),fmaxf(s[2],s[3])),
                       fmaxf(fmaxf(s[4],s[5]),fmaxf(s[6],s[7])));
      const float mnew = fmaxf(m, mc);
      const float corr = fexp2(L2E*(m - mnew));   // m=-inf first chunk -> 0
      l *= corr;
      #pragma unroll
      for (int d=0;d<10;d++) acc[d]*=corr;
      const float mB = L2E*mnew;
      #pragma unroll
      for (int u2=0;u2<4;u2++){
        const float p0 = fexp2(fmaf(s[2*u2],  L2E, -mB));
        const float p1 = fexp2(fmaf(s[2*u2+1],L2E, -mB));
        l += p0; l += p1;
        const float4* vp = (const float4*)(vb + (c8+2*u2)*10);
        const float4 A=vp[0], B4=vp[1], C4=vp[2], D4=vp[3], E4=vp[4];
        acc[0]=fmaf(p0,A.x,acc[0]);  acc[1]=fmaf(p0,A.y,acc[1]);
        acc[2]=fmaf(p0,A.z,acc[2]);  acc[3]=fmaf(p0,A.w,acc[3]);
        acc[4]=fmaf(p0,B4.x,acc[4]); acc[5]=fmaf(p0,B4.y,acc[5]);
        acc[6]=fmaf(p0,B4.z,acc[6]); acc[7]=fmaf(p0,B4.w,acc[7]);
        acc[8]=fmaf(p0,C4.x,acc[8]); acc[9]=fmaf(p0,C4.y,acc[9]);
        acc[0]=fmaf(p1,C4.z,acc[0]); acc[1]=fmaf(p1,C4.w,acc[1]);
        acc[2]=fmaf(p1,D4.x,acc[2]); acc[3]=fmaf(p1,D4.y,acc[3]);
        acc[4]=fmaf(p1,D4.z,acc[4]); acc[5]=fmaf(p1,D4.w,acc[5]);
        acc[6]=fmaf(p1,E4.x,acc[6]); acc[7]=fmaf(p1,E4.y,acc[7]);
        acc[8]=fmaf(p1,E4.z,acc[8]); acc[9]=fmaf(p1,E4.w,acc[9]);
      }
      m = mnew;
    }
  }
  float4 w0,w1,w2;
  w0.x=m;      w0.y=l;      w0.z=acc[0]; w0.w=acc[1];
  w1.x=acc[2]; w1.y=acc[3]; w1.z=acc[4]; w1.w=acc[5];
  w2.x=acc[6]; w2.y=acc[7]; w2.z=acc[8]; w2.w=acc[9];
  float4* pp4 = (float4*)(part + ((size_t)(head*Bsz + qr)*gridDim.z + ks)*12);
  pp4[0]=w0; pp4[1]=w1; pp4[2]=w2;
}

// ---------------------------------------------------------------------------
// Kernel 3 (R10, frozen): fused merge + out_proj + LN + MLP + LN + head.
// ---------------------------------------------------------------------------
extern "C" __global__ void __launch_bounds__(256)
tail_k(const float* __restrict__ part, int ns, const float* __restrict__ hn,
       const float* __restrict__ out_proj_w, const float* __restrict__ out_proj_b,
       const float* __restrict__ fc1_w, const float* __restrict__ fc1_b,
       const float* __restrict__ fc2_w, const float* __restrict__ fc2_b,
       const float* __restrict__ ln_g, const float* __restrict__ ln_b,
       const float* __restrict__ out_w, const float* __restrict__ out_b,
       float* __restrict__ out)
{
  __shared__ __align__(16) float buf[4][32];
  __shared__ float wl[2880];   // [0]=out_proj_w 900, [900]=fc1_w, [1800]=fc2_w, [2700]=out_w 90
  const int tidb = threadIdx.x;
  for (int i=tidb;i<900;i+=256) wl[i]       = out_proj_w[i];
  for (int i=tidb;i<900;i+=256) wl[900+i]   = fc1_w[i];
  for (int i=tidb;i<900;i+=256) wl[1800+i]  = fc2_w[i];
  if (tidb < 90) wl[2700+tidb] = out_w[tidb];
  const int wave = tidb >> 6;
  const int lane = tidb & 63;
  const int b = blockIdx.x*4 + wave;
  const bool act = (lane < NE);
  if (lane < 32) buf[wave][lane] = 0.f;
  __syncthreads();
  if (act) {
    const int head = lane/10, dd = lane%10;
    const float* p = part + ((size_t)(head*Bsz + b)*ns)*12;
    float M = -INFINITY, L = 0.f, O = 0.f;
    for (int i=0;i<ns;i++){
      const float mi = p[i*12], li = p[i*12+1], ai = p[i*12+2+dd];
      const float Mn = fmaxf(M, mi);
      const float cw = fexp2(L2E*(M - Mn));
      const float wi = fexp2(L2E*(mi - Mn));
      L = fmaf(li, wi, L*cw);
      O = fmaf(ai, wi, O*cw);
      M = Mn;
    }
    buf[wave][lane] = O / L;
  }
  __builtin_amdgcn_wave_barrier();
  float arr[32];
  loadarr32(arr, &buf[wave][0]);
  const float hv = act ? hn[b*NE+lane] : 0.f;
  float x = 0.f;
  if (act) {
    float a = out_proj_b[lane];
    #pragma unroll
    for (int k2=0;k2<NE;k2++) a = fmaf(wl[lane*NE+k2], arr[k2], a);
    x = a + hv;                       // attn_out + h_n
  }
  // LN1
  __builtin_amdgcn_wave_barrier();
  if (act) buf[wave][lane] = x;
  __builtin_amdgcn_wave_barrier();
  loadarr32(arr, &buf[wave][0]);
  float s1=0.f, s2=0.f;
  #pragma unroll
  for (int k2=0;k2<32;k2++){ s1+=arr[k2]; s2=fmaf(arr[k2],arr[k2],s2); }
  float mu = s1*(1.f/30.f);
  float var = s2*(1.f/30.f) - mu*mu;
  float rs = rsqrtf(var + 1e-5f);
  float x1 = 0.f;
  if (act) x1 = fmaf((x-mu)*rs, ln_g[lane], ln_b[lane]);
  // fc1 + exact GELU
  __builtin_amdgcn_wave_barrier();
  if (act) buf[wave][lane] = x1;
  __builtin_amdgcn_wave_barrier();
  loadarr32(arr, &buf[wave][0]);
  float gv = 0.f;
  if (act) {
    float a = fc1_b[lane];
    #pragma unroll
    for (int k2=0;k2<NE;k2++) a = fmaf(wl[900+lane*NE+k2], arr[k2], a);
    gv = 0.5f*a*(1.f + erff(a*0.70710678118654752f));
  }
  // fc2
  __builtin_amdgcn_wave_barrier();
  if (act) buf[wave][lane] = gv;
  __builtin_amdgcn_wave_barrier();
  loadarr32(arr, &buf[wave][0]);
  float y = 0.f;
  if (act) {
    float a = fc2_b[lane];
    #pragma unroll
    for (int k2=0;k2<NE;k2++) a = fmaf(wl[1800+lane*NE+k2], arr[k2], a);
    y = x1 + a;                        // residual x1 + fc
  }
  // LN2
  __builtin_amdgcn_wave_barrier();
  if (act) buf[wave][lane] = y;
  __builtin_amdgcn_wave_barrier();
  loadarr32(arr, &buf[wave][0]);
  s1=0.f; s2=0.f;
  #pragma unroll
  for (int k2=0;k2<32;k2++){ s1+=arr[k2]; s2=fmaf(arr[k2],arr[k2],s2); }
  mu = s1*(1.f/30.f);
  var = s2*(1.f/30.f) - mu*mu;
  rs = rsqrtf(var + 1e-5f);
  float x2 = 0.f;
  if (act) x2 = fmaf((y-mu)*rs, ln_g[lane], ln_b[lane]);
  // head: [3,30]
  __builtin_amdgcn_wave_barrier();
  if (act) buf[wave][lane] = x2;
  __builtin_amdgcn_wave_barrier();
  loadarr32(arr, &buf[wave][0]);
  if (lane < 3) {
    float a = out_b[lane];
    #pragma unroll
    for (int k2=0;k2<NE;k2++) a = fmaf(wl[2700+lane*NE+k2], arr[k2], a);
    out[b*3 + lane] = a;
  }
}

extern "C" void kernel_launch(void* const* d_in, const int* in_sizes, int n_in,
                              void* d_out, int out_size, void* d_ws, size_t ws_size,
                              hipStream_t stream)
{
  const float* input      = (const float*)d_in[0];
  const float* w_ih       = (const float*)d_in[1];
  const float* w_hh       = (const float*)d_in[2];
  const float* b_ih       = (const float*)d_in[3];
  const float* b_hh       = (const float*)d_in[4];
  const float* in_proj_w  = (const float*)d_in[5];
  const float* in_proj_b  = (const float*)d_in[6];
  const float* out_proj_w = (const float*)d_in[7];
  const float* out_proj_b = (const float*)d_in[8];
  const float* fc1_w      = (const float*)d_in[9];
  const float* fc1_b      = (const float*)d_in[10];
  const float* fc2_w      = (const float*)d_in[11];
  const float* fc2_b      = (const float*)d_in[12];
  const float* ln_g       = (const float*)d_in[13];
  const float* ln_b       = (const float*)d_in[14];
  const float* out_w      = (const float*)d_in[15];
  const float* out_b      = (const float*)d_in[16];

  float* ws = (float*)d_ws;
  float* qo   = ws;                 // [3][4096][10]
  float* ko   = ws + 122880;        // [3][4096][10]
  float* vo   = ws + 245760;        // [3][4096][10]
  float* hn   = ws + 368640;        // [4096][30]
  float* part = ws + 491520;        // [3][4096][NS][12]

  const size_t need32 = ((size_t)491520 + (size_t)3*4096*32*12) * 4;
  const size_t need16 = ((size_t)491520 + (size_t)3*4096*16*12) * 4;
  const int NS = (ws_size >= need32) ? 32 : (ws_size >= need16) ? 16 : 8;

  lstm_k<<<Bsz/16, 512, 0, stream>>>(input, w_ih, w_hh, b_ih, b_hh,
                                     in_proj_w, in_proj_b, qo, ko, vo, hn);
  attn_part<<<dim3(Bsz/256, 3, NS), 256, 0, stream>>>(qo, ko, vo, part, Bsz/NS);
  tail_k<<<Bsz/4, 256, 0, stream>>>(part, NS, hn, out_proj_w, out_proj_b,
                                    fc1_w, fc1_b, fc2_w, fc2_b,
                                    ln_g, ln_b, out_w, out_b, (float*)d_out);
}